// Round 5
// baseline (460.869 us; speedup 1.0000x reference)
//
#include <hip/hip_runtime.h>

#define T_STEPS 512
#define IN_DIM 11
#define ROW_PAD 12                  // x row padded to 12 floats in LDS
#define H_DIM 16
#define ROW_F (T_STEPS * IN_DIM)    // 5632 floats per batch row
#define CHUNK_T 16                  // t-steps per x chunk
#define CHUNK_F (CHUNK_T * IN_DIM)  // 176 source floats per chunk
#define N_CHUNK (T_STEPS / CHUNK_T)
#define LOG2E 1.44269504088896340736f

typedef float v2f __attribute__((ext_vector_type(2)));

// Packed fp32 FMA (v_pk_fma_f32): 2 MACs/instr, full rate.
__device__ __forceinline__ v2f pk_fma(v2f a, v2f b, v2f c) {
    v2f d;
    asm("v_pk_fma_f32 %0, %1, %2, %3" : "=v"(d) : "v"(a), "v"(b), "v"(c));
    return d;
}

// DPP quad_perm broadcast within each group of 4 lanes.
template<int CTRL>
__device__ __forceinline__ float qperm(float v) {
    return __builtin_bit_cast(float,
        __builtin_amdgcn_update_dpp(0, __builtin_bit_cast(int, v),
                                    CTRL, 0xf, 0xf, true));
}

__device__ __forceinline__ float bcast_lane(float v, int l) {
    return __builtin_bit_cast(float,
        __builtin_amdgcn_readlane(__builtin_bit_cast(int, v), l));
}

// One wave per batch element; lane = 4*r + gate (i,f,g,o quads).
// KEY (round 5): amdgpu_waves_per_eu(4,4). The allocator's default target is
// 8 waves/EU -> 64 arch VGPRs, which cannot hold the 60 pinned weight VGPRs;
// rounds 2-4 all showed VGPR_Count=64 + ~85 phantom VALU instrs/step (AGPR
// bounces on weight operands). The grid supplies exactly 4 waves/EU, so pin
// the occupancy target there and give the allocator the full 128-VGPR budget.
__global__ __launch_bounds__(256)
__attribute__((amdgpu_waves_per_eu(4, 4)))
void lstm2_head(
    const float* __restrict__ x,
    const float* __restrict__ Wih1, const float* __restrict__ Whh1,
    const float* __restrict__ bih1, const float* __restrict__ bhh1,
    const float* __restrict__ Wih2, const float* __restrict__ Whh2,
    const float* __restrict__ bih2, const float* __restrict__ bhh2,
    const float* __restrict__ Wd1, const float* __restrict__ bd1,
    const float* __restrict__ Wd2, const float* __restrict__ bd2,
    const float* __restrict__ Wd3, const float* __restrict__ bd3,
    float* __restrict__ out)
{
    __shared__ float xlds[4][2][212];   // [wave][buf][padded chunk]
    __shared__ v2f   shh[4][2][8];      // [wave][layer][h pairs]

    const int lane = threadIdx.x & 63;
    const int wid = __builtin_amdgcn_readfirstlane((int)(threadIdx.x >> 6));
    const int b = blockIdx.x * 4 + wid;

    const int r   = lane >> 2;          // hidden index 0..15
    const int gt  = lane & 3;           // 0:i 1:f 2:g(tanh) 3:o
    const int row = gt * H_DIM + r;     // row in packed 4H weights

    const bool is_t = (gt == 2);
    const float M   = is_t ? (-2.0f * LOG2E) : (-LOG2E);
    const float vAa = is_t ? 2.0f : 1.0f;
    const float vBc = is_t ? -1.0f : 0.0f;

    // ---- per-lane weights (M-scaled), packed in v2f, pinned ----
    v2f wi1p[6], wh1p[8], wi2p[8], wh2p[8];
    #pragma unroll
    for (int j = 0; j < 5; ++j)
        wi1p[j] = (v2f){M * Wih1[row * IN_DIM + 2 * j], M * Wih1[row * IN_DIM + 2 * j + 1]};
    wi1p[5] = (v2f){M * Wih1[row * IN_DIM + 10], 0.0f};   // pad weight = 0
    #pragma unroll
    for (int j = 0; j < 8; ++j) {
        wh1p[j] = (v2f){M * Whh1[row * H_DIM + 2 * j], M * Whh1[row * H_DIM + 2 * j + 1]};
        wi2p[j] = (v2f){M * Wih2[row * H_DIM + 2 * j], M * Wih2[row * H_DIM + 2 * j + 1]};
        wh2p[j] = (v2f){M * Whh2[row * H_DIM + 2 * j], M * Whh2[row * H_DIM + 2 * j + 1]};
    }
    v2f bb1v = (v2f){M * (bih1[row] + bhh1[row]), 0.0f};
    v2f bb2v = (v2f){M * (bih2[row] + bhh2[row]), 0.0f};
    #pragma unroll
    for (int j = 0; j < 6; ++j) asm volatile("" : "+v"(wi1p[j]));
    #pragma unroll
    for (int j = 0; j < 8; ++j) {
        asm volatile("" : "+v"(wh1p[j]));
        asm volatile("" : "+v"(wi2p[j]));
        asm volatile("" : "+v"(wh2p[j]));
    }
    asm volatile("" : "+v"(bb1v));
    asm volatile("" : "+v"(bb2v));

    const float* __restrict__ xb = x + (size_t)b * ROW_F;
    float* const xl0 = &xlds[wid][0][0];
    float* const xl1 = &xlds[wid][1][0];
    v2f* const h1mem = &shh[wid][0][0];
    v2f* const h2mem = &shh[wid][1][0];

    // init h state + zero x pad slots (same-wave ordering, no barrier needed)
    ((float*)h1mem)[r & 15] = 0.0f;
    ((float*)h2mem)[r & 15] = 0.0f;
    if (lane < 32) {
        const int buf = lane >> 4, rr = lane & 15;
        xlds[wid][buf][rr * ROW_PAD + IN_DIM] = 0.0f;       // pad slot
    }

    // staging offsets: source float f -> padded slot (f/11)*12 + f%11
    const int f1i = lane, f2i = lane + 64, f3i = lane + 128;
    const int p1 = (f1i / IN_DIM) * ROW_PAD + (f1i % IN_DIM);
    const int p2 = (f2i / IN_DIM) * ROW_PAD + (f2i % IN_DIM);
    const int p3 = (f3i / IN_DIM) * ROW_PAD + (f3i % IN_DIM);

    // prologue: global-load chunk 0
    float gl0 = xb[f1i];
    float gl1 = xb[f2i];
    float gl2 = xb[min(f3i, ROW_F - 1)];

    float c1 = 0.f, c2 = 0.f, h2v = 0.f, ssum = 0.f;
    // register-resident h pairs (carried across steps)
    v2f h1r[8], h2r[8];
    #pragma unroll
    for (int j = 0; j < 8; ++j) { h1r[j] = (v2f){0.f, 0.f}; h2r[j] = (v2f){0.f, 0.f}; }

    for (int ck = 0; ck < N_CHUNK; ++ck) {
        float* const xbuf = (ck & 1) ? xl1 : xl0;
        xbuf[p1] = gl0;
        xbuf[p2] = gl1;
        xbuf[p3] = gl2;
        if (ck + 1 < N_CHUNK) {
            const int base = (ck + 1) * CHUNK_F;
            gl0 = xb[base + f1i];
            gl1 = xb[base + f2i];
            gl2 = xb[min(base + f3i, ROW_F - 1)];
        }

        #pragma unroll
        for (int t2 = 0; t2 < CHUNK_T; ++t2) {
            const v2f* const xr = (const v2f*)(xbuf + t2 * ROW_PAD);

            // ---- layer-2 recurrent dot (h2r from prev step, reg-resident) ----
            v2f a2p = pk_fma(wh2p[0], h2r[0], bb2v);
            #pragma unroll
            for (int j = 1; j < 8; ++j) a2p = pk_fma(wh2p[j], h2r[j], a2p);

            // ---- layer-1 preact: x-dot (LDS pairs) + recurrent (h1r regs) ----
            v2f a1p = pk_fma(wi1p[0], xr[0], bb1v);
            #pragma unroll
            for (int j = 1; j < 6; ++j) a1p = pk_fma(wi1p[j], xr[j], a1p);
            #pragma unroll
            for (int j = 0; j < 8; ++j) a1p = pk_fma(wh1p[j], h1r[j], a1p);

            // ---- layer 1 activation + cell ----
            const float g1 = a1p.x + a1p.y;
            const float a1 = __builtin_fmaf(vAa,
                __builtin_amdgcn_rcpf(1.0f + __builtin_amdgcn_exp2f(g1)), vBc);
            {
                const float gi = qperm<0x00>(a1);
                const float gf = qperm<0x55>(a1);
                const float gg = qperm<0xAA>(a1);
                const float go = qperm<0xFF>(a1);
                c1 = __builtin_fmaf(gf, c1, gi * gg);
                const float tc = __builtin_fmaf(2.0f,
                    __builtin_amdgcn_rcpf(1.0f +
                        __builtin_amdgcn_exp2f(-2.0f * LOG2E * c1)), -1.0f);
                ((float*)h1mem)[r] = go * tc;       // quad-replicated write
            }
            // read fresh h1 pairs ONCE: used for wi2 now, wh1 next step
            #pragma unroll
            for (int j = 0; j < 8; ++j) h1r[j] = h1mem[j];

            #pragma unroll
            for (int j = 0; j < 8; ++j) a2p = pk_fma(wi2p[j], h1r[j], a2p);

            // ---- layer 2 activation + cell ----
            const float g2 = a2p.x + a2p.y;
            const float a2 = __builtin_fmaf(vAa,
                __builtin_amdgcn_rcpf(1.0f + __builtin_amdgcn_exp2f(g2)), vBc);
            {
                const float gi = qperm<0x00>(a2);
                const float gf = qperm<0x55>(a2);
                const float gg = qperm<0xAA>(a2);
                const float go = qperm<0xFF>(a2);
                c2 = __builtin_fmaf(gf, c2, gi * gg);
                const float tc = __builtin_fmaf(2.0f,
                    __builtin_amdgcn_rcpf(1.0f +
                        __builtin_amdgcn_exp2f(-2.0f * LOG2E * c2)), -1.0f);
                h2v = go * tc;                      // quad-replicated
                ((float*)h2mem)[r] = h2v;
            }
            // read fresh h2 pairs ONCE for next step's wh2 dot
            #pragma unroll
            for (int j = 0; j < 8; ++j) h2r[j] = h2mem[j];

            ssum += __builtin_amdgcn_exp2f(LOG2E * h2v);
        }
    }

    // s[b,k] = exp(h2[T-1,k]) / sum_t exp(h2[t,k]); h2v replicated per quad.
    const float sv = __builtin_amdgcn_exp2f(LOG2E * h2v) / ssum;

    float ssb[H_DIM];
    #pragma unroll
    for (int k = 0; k < H_DIM; ++k) ssb[k] = bcast_lane(sv, 4 * k);

    // Dense head 16 -> 8 -> 8 -> 3 + softmax (one-time epilogue).
    const int r8 = lane & 7;
    float acc1 = bd1[r8];
    #pragma unroll
    for (int k = 0; k < H_DIM; ++k)
        acc1 = __builtin_fmaf(Wd1[r8 * H_DIM + k], ssb[k], acc1);

    float d1s[8];
    #pragma unroll
    for (int j = 0; j < 8; ++j) d1s[j] = bcast_lane(acc1, j);

    float acc2 = bd2[r8];
    #pragma unroll
    for (int k = 0; k < 8; ++k)
        acc2 = __builtin_fmaf(Wd2[r8 * 8 + k], d1s[k], acc2);

    float d2s[8];
    #pragma unroll
    for (int j = 0; j < 8; ++j) d2s[j] = bcast_lane(acc2, j);

    float lg = 0.f;
    if (lane < 3) {
        lg = bd3[lane];
        #pragma unroll
        for (int k = 0; k < 8; ++k)
            lg = __builtin_fmaf(Wd3[lane * 8 + k], d2s[k], lg);
    }
    const float l0 = bcast_lane(lg, 0);
    const float l1 = bcast_lane(lg, 1);
    const float l2 = bcast_lane(lg, 2);
    const float mx = fmaxf(l0, fmaxf(l1, l2));
    const float e0 = __builtin_amdgcn_exp2f(LOG2E * (l0 - mx));
    const float e1 = __builtin_amdgcn_exp2f(LOG2E * (l1 - mx));
    const float e2 = __builtin_amdgcn_exp2f(LOG2E * (l2 - mx));
    const float inv = 1.0f / (e0 + e1 + e2);
    if (lane < 3) {
        const float ev = (lane == 0) ? e0 : ((lane == 1) ? e1 : e2);
        out[b * 3 + lane] = ev * inv;
    }
}

extern "C" void kernel_launch(void* const* d_in, const int* in_sizes, int n_in,
                              void* d_out, int out_size, void* d_ws, size_t ws_size,
                              hipStream_t stream) {
    (void)in_sizes; (void)n_in; (void)out_size; (void)d_ws; (void)ws_size;
    const float* x    = (const float*)d_in[0];
    const float* Wih1 = (const float*)d_in[1];
    const float* Whh1 = (const float*)d_in[2];
    const float* bih1 = (const float*)d_in[3];
    const float* bhh1 = (const float*)d_in[4];
    const float* Wih2 = (const float*)d_in[5];
    const float* Whh2 = (const float*)d_in[6];
    const float* bih2 = (const float*)d_in[7];
    const float* bhh2 = (const float*)d_in[8];
    const float* Wd1  = (const float*)d_in[9];
    const float* bd1  = (const float*)d_in[10];
    const float* Wd2  = (const float*)d_in[11];
    const float* bd2  = (const float*)d_in[12];
    const float* Wd3  = (const float*)d_in[13];
    const float* bd3  = (const float*)d_in[14];

    lstm2_head<<<dim3(4096 / 4), dim3(256), 0, stream>>>(
        x, Wih1, Whh1, bih1, bhh1, Wih2, Whh2, bih2, bhh2,
        Wd1, bd1, Wd2, bd2, Wd3, bd3, (float*)d_out);
}

// Round 6
// 455.280 us; speedup vs baseline: 1.0123x; 1.0123x over previous
//
#include <hip/hip_runtime.h>

#define T_STEPS 512
#define IN_DIM 11
#define ROW_PAD 12                  // x row padded to 12 f16 in LDS (24 B, 8-B aligned)
#define H_DIM 16
#define ROW_F (T_STEPS * IN_DIM)    // 5632 floats per batch row
#define CHUNK_T 16                  // t-steps per x chunk
#define CHUNK_F (CHUNK_T * IN_DIM)  // 176 source floats per chunk
#define N_CHUNK (T_STEPS / CHUNK_T)
#define LOG2E 1.44269504088896340736f

typedef _Float16 v2h __attribute__((ext_vector_type(2)));
typedef _Float16 v8h __attribute__((ext_vector_type(8)));

// v_dot2_f32_f16: D = a.x*b.x + a.y*b.y + c (f16 products exact in f32).
#if __has_builtin(__builtin_amdgcn_fdot2)
__device__ __forceinline__ float fdot2(v2h a, v2h b, float c) {
    return __builtin_amdgcn_fdot2(a, b, c, false);
}
#else
__device__ __forceinline__ float fdot2(v2h a, v2h b, float c) {
    float d;
    asm("v_dot2_f32_f16 %0, %1, %2, %3" : "=v"(d) : "v"(a), "v"(b), "v"(c));
    return d;
}
#endif

// DPP quad_perm broadcast within each group of 4 lanes.
template<int CTRL>
__device__ __forceinline__ float qperm(float v) {
    return __builtin_bit_cast(float,
        __builtin_amdgcn_update_dpp(0, __builtin_bit_cast(int, v),
                                    CTRL, 0xf, 0xf, true));
}

__device__ __forceinline__ float bcast_lane(float v, int l) {
    return __builtin_bit_cast(float,
        __builtin_amdgcn_readlane(__builtin_bit_cast(int, v), l));
}

// One wave per batch element; lane = 4*r + gate (i,f,g,o quads).
// ROUND 6: all weight rows + h broadcasts stored as packed f16 and consumed by
// v_dot2_f32_f16 (exact f32 accumulate). Register demand drops to ~63 arch
// VGPRs -- under the allocator's 64-VGPR bucket that rounds 2-5 could not
// escape (VGPR_Count pinned at 64 with ~140 cyc/step of AGPR-bounce traffic).
// Cell math / activations stay fp32; softmax-over-time attenuates f16 drift
// by ~3 orders of magnitude at the output.
__global__ __launch_bounds__(256)
__attribute__((amdgpu_waves_per_eu(4, 4)))
void lstm2_head(
    const float* __restrict__ x,
    const float* __restrict__ Wih1, const float* __restrict__ Whh1,
    const float* __restrict__ bih1, const float* __restrict__ bhh1,
    const float* __restrict__ Wih2, const float* __restrict__ Whh2,
    const float* __restrict__ bih2, const float* __restrict__ bhh2,
    const float* __restrict__ Wd1, const float* __restrict__ bd1,
    const float* __restrict__ Wd2, const float* __restrict__ bd2,
    const float* __restrict__ Wd3, const float* __restrict__ bd3,
    float* __restrict__ out)
{
    __shared__ _Float16 xlds[4][2][216];   // [wave][buf][padded chunk f16]
    __shared__ v8h      shh8[4][2][2];     // [wave][layer][16 f16 as 2x v8h]

    const int lane = threadIdx.x & 63;
    const int wid = __builtin_amdgcn_readfirstlane((int)(threadIdx.x >> 6));
    const int b = blockIdx.x * 4 + wid;

    const int r   = lane >> 2;          // hidden index 0..15
    const int gt  = lane & 3;           // 0:i 1:f 2:g(tanh) 3:o
    const int row = gt * H_DIM + r;     // row in packed 4H weights

    const bool is_t = (gt == 2);
    const float M   = is_t ? (-2.0f * LOG2E) : (-LOG2E);
    const float vAa = is_t ? 2.0f : 1.0f;
    const float vBc = is_t ? -1.0f : 0.0f;

    // ---- per-lane weights, M-scaled, packed f16 pairs ----
    v2h wi1h[6], wh1h[8], wi2h[8], wh2h[8];
    #pragma unroll
    for (int j = 0; j < 5; ++j)
        wi1h[j] = (v2h){(_Float16)(M * Wih1[row * IN_DIM + 2 * j]),
                        (_Float16)(M * Wih1[row * IN_DIM + 2 * j + 1])};
    wi1h[5] = (v2h){(_Float16)(M * Wih1[row * IN_DIM + 10]), (_Float16)0.0f};
    #pragma unroll
    for (int j = 0; j < 8; ++j) {
        wh1h[j] = (v2h){(_Float16)(M * Whh1[row * H_DIM + 2 * j]),
                        (_Float16)(M * Whh1[row * H_DIM + 2 * j + 1])};
        wi2h[j] = (v2h){(_Float16)(M * Wih2[row * H_DIM + 2 * j]),
                        (_Float16)(M * Wih2[row * H_DIM + 2 * j + 1])};
        wh2h[j] = (v2h){(_Float16)(M * Whh2[row * H_DIM + 2 * j]),
                        (_Float16)(M * Whh2[row * H_DIM + 2 * j + 1])};
    }
    const float bb1 = M * (bih1[row] + bhh1[row]);
    const float bb2 = M * (bih2[row] + bhh2[row]);
    #pragma unroll
    for (int j = 0; j < 6; ++j) asm volatile("" : "+v"(wi1h[j]));
    #pragma unroll
    for (int j = 0; j < 8; ++j) {
        asm volatile("" : "+v"(wh1h[j]));
        asm volatile("" : "+v"(wi2h[j]));
        asm volatile("" : "+v"(wh2h[j]));
    }

    const float* __restrict__ xb = x + (size_t)b * ROW_F;
    _Float16* const xl0 = &xlds[wid][0][0];
    _Float16* const xl1 = &xlds[wid][1][0];
    _Float16* const h1w = (_Float16*)&shh8[wid][0][0];
    _Float16* const h2w = (_Float16*)&shh8[wid][1][0];

    // init h slabs + x pad slots (per-wave LDS, same-wave ordering, no barrier)
    h1w[r] = (_Float16)0.0f;
    h2w[r] = (_Float16)0.0f;
    if (lane < 32) {
        const int buf = lane >> 4, rr = lane & 15;
        xlds[wid][buf][rr * ROW_PAD + IN_DIM] = (_Float16)0.0f;  // pad slot
    }

    // staging: source float f -> padded f16 slot (f/11)*12 + f%11
    const int f1i = lane, f2i = lane + 64, f3i = lane + 128;
    const int p1 = (f1i / IN_DIM) * ROW_PAD + (f1i % IN_DIM);
    const int p2 = (f2i / IN_DIM) * ROW_PAD + (f2i % IN_DIM);
    const int p3 = (f3i / IN_DIM) * ROW_PAD + (f3i % IN_DIM);

    // prologue: global-load chunk 0
    float gl0 = xb[f1i];
    float gl1 = xb[f2i];
    float gl2 = xb[min(f3i, ROW_F - 1)];

    float c1 = 0.f, c2 = 0.f, h2v = 0.f, ssum = 0.f;
    // register-resident f16 h pairs (carried across steps)
    v2h h1r[8], h2r[8];
    #pragma unroll
    for (int j = 0; j < 8; ++j) {
        h1r[j] = (v2h){(_Float16)0.f, (_Float16)0.f};
        h2r[j] = (v2h){(_Float16)0.f, (_Float16)0.f};
    }

    for (int ck = 0; ck < N_CHUNK; ++ck) {
        _Float16* const xbuf = (ck & 1) ? xl1 : xl0;
        xbuf[p1] = (_Float16)gl0;
        xbuf[p2] = (_Float16)gl1;
        xbuf[p3] = (_Float16)gl2;
        if (ck + 1 < N_CHUNK) {
            const int base = (ck + 1) * CHUNK_F;
            gl0 = xb[base + f1i];
            gl1 = xb[base + f2i];
            gl2 = xb[min(base + f3i, ROW_F - 1)];
        }

        #pragma unroll
        for (int t2 = 0; t2 < CHUNK_T; ++t2) {
            const v2h* const xr = (const v2h*)(xbuf + t2 * ROW_PAD);

            // ---- layer-2 recurrent dot (h2r reg-resident, split chains) ----
            float a2 = bb2, b2 = 0.f;
            #pragma unroll
            for (int j = 0; j < 4; ++j) {
                a2 = fdot2(wh2h[j],     h2r[j],     a2);
                b2 = fdot2(wh2h[j + 4], h2r[j + 4], b2);
            }

            // ---- layer-1 preact: x (LDS f16 pairs) + recurrent (regs) ----
            float a1 = bb1, b1 = 0.f;
            #pragma unroll
            for (int j = 0; j < 3; ++j) {
                a1 = fdot2(wi1h[j],     xr[j],     a1);
                b1 = fdot2(wi1h[j + 3], xr[j + 3], b1);
            }
            #pragma unroll
            for (int j = 0; j < 4; ++j) {
                a1 = fdot2(wh1h[j],     h1r[j],     a1);
                b1 = fdot2(wh1h[j + 4], h1r[j + 4], b1);
            }

            // ---- layer 1 activation + cell (fp32) ----
            const float g1 = a1 + b1;
            const float act1 = __builtin_fmaf(vAa,
                __builtin_amdgcn_rcpf(1.0f + __builtin_amdgcn_exp2f(g1)), vBc);
            {
                const float gi = qperm<0x00>(act1);
                const float gf = qperm<0x55>(act1);
                const float gg = qperm<0xAA>(act1);
                const float go = qperm<0xFF>(act1);
                c1 = __builtin_fmaf(gf, c1, gi * gg);
                const float tc = __builtin_fmaf(2.0f,
                    __builtin_amdgcn_rcpf(1.0f +
                        __builtin_amdgcn_exp2f(-2.0f * LOG2E * c1)), -1.0f);
                h1w[r] = (_Float16)(go * tc);       // quad-replicated b16 write
            }
            // read fresh h1 pairs ONCE: wi2 now, wh1 next step
            {
                const v2h* hp = (const v2h*)h1w;
                #pragma unroll
                for (int j = 0; j < 8; ++j) h1r[j] = hp[j];
            }
            #pragma unroll
            for (int j = 0; j < 4; ++j) {
                a2 = fdot2(wi2h[j],     h1r[j],     a2);
                b2 = fdot2(wi2h[j + 4], h1r[j + 4], b2);
            }

            // ---- layer 2 activation + cell (fp32) ----
            const float g2 = a2 + b2;
            const float act2 = __builtin_fmaf(vAa,
                __builtin_amdgcn_rcpf(1.0f + __builtin_amdgcn_exp2f(g2)), vBc);
            {
                const float gi = qperm<0x00>(act2);
                const float gf = qperm<0x55>(act2);
                const float gg = qperm<0xAA>(act2);
                const float go = qperm<0xFF>(act2);
                c2 = __builtin_fmaf(gf, c2, gi * gg);
                const float tc = __builtin_fmaf(2.0f,
                    __builtin_amdgcn_rcpf(1.0f +
                        __builtin_amdgcn_exp2f(-2.0f * LOG2E * c2)), -1.0f);
                h2v = go * tc;                      // fp32, quad-replicated
                h2w[r] = (_Float16)h2v;
            }
            // read fresh h2 pairs ONCE for next step's wh2 dot
            {
                const v2h* hp = (const v2h*)h2w;
                #pragma unroll
                for (int j = 0; j < 8; ++j) h2r[j] = hp[j];
            }

            ssum += __builtin_amdgcn_exp2f(LOG2E * h2v);
        }
    }

    // s[b,k] = exp(h2[T-1,k]) / sum_t exp(h2[t,k]); h2v replicated per quad.
    const float sv = __builtin_amdgcn_exp2f(LOG2E * h2v) / ssum;

    float ssb[H_DIM];
    #pragma unroll
    for (int k = 0; k < H_DIM; ++k) ssb[k] = bcast_lane(sv, 4 * k);

    // Dense head 16 -> 8 -> 8 -> 3 + softmax (one-time epilogue, fp32).
    const int r8 = lane & 7;
    float acc1 = bd1[r8];
    #pragma unroll
    for (int k = 0; k < H_DIM; ++k)
        acc1 = __builtin_fmaf(Wd1[r8 * H_DIM + k], ssb[k], acc1);

    float d1s[8];
    #pragma unroll
    for (int j = 0; j < 8; ++j) d1s[j] = bcast_lane(acc1, j);

    float acc2 = bd2[r8];
    #pragma unroll
    for (int k = 0; k < 8; ++k)
        acc2 = __builtin_fmaf(Wd2[r8 * 8 + k], d1s[k], acc2);

    float d2s[8];
    #pragma unroll
    for (int j = 0; j < 8; ++j) d2s[j] = bcast_lane(acc2, j);

    float lg = 0.f;
    if (lane < 3) {
        lg = bd3[lane];
        #pragma unroll
        for (int k = 0; k < 8; ++k)
            lg = __builtin_fmaf(Wd3[lane * 8 + k], d2s[k], lg);
    }
    const float l0 = bcast_lane(lg, 0);
    const float l1 = bcast_lane(lg, 1);
    const float l2 = bcast_lane(lg, 2);
    const float mx = fmaxf(l0, fmaxf(l1, l2));
    const float e0 = __builtin_amdgcn_exp2f(LOG2E * (l0 - mx));
    const float e1 = __builtin_amdgcn_exp2f(LOG2E * (l1 - mx));
    const float e2 = __builtin_amdgcn_exp2f(LOG2E * (l2 - mx));
    const float inv = 1.0f / (e0 + e1 + e2);
    if (lane < 3) {
        const float ev = (lane == 0) ? e0 : ((lane == 1) ? e1 : e2);
        out[b * 3 + lane] = ev * inv;
    }
}

extern "C" void kernel_launch(void* const* d_in, const int* in_sizes, int n_in,
                              void* d_out, int out_size, void* d_ws, size_t ws_size,
                              hipStream_t stream) {
    (void)in_sizes; (void)n_in; (void)out_size; (void)d_ws; (void)ws_size;
    const float* x    = (const float*)d_in[0];
    const float* Wih1 = (const float*)d_in[1];
    const float* Whh1 = (const float*)d_in[2];
    const float* bih1 = (const float*)d_in[3];
    const float* bhh1 = (const float*)d_in[4];
    const float* Wih2 = (const float*)d_in[5];
    const float* Whh2 = (const float*)d_in[6];
    const float* bih2 = (const float*)d_in[7];
    const float* bhh2 = (const float*)d_in[8];
    const float* Wd1  = (const float*)d_in[9];
    const float* bd1  = (const float*)d_in[10];
    const float* Wd2  = (const float*)d_in[11];
    const float* bd2  = (const float*)d_in[12];
    const float* Wd3  = (const float*)d_in[13];
    const float* bd3  = (const float*)d_in[14];

    lstm2_head<<<dim3(4096 / 4), dim3(256), 0, stream>>>(
        x, Wih1, Whh1, bih1, bhh1, Wih2, Whh2, bih2, bhh2,
        Wd1, bd1, Wd2, bd2, Wd3, bd3, (float*)d_out);
}